// Round 6
// baseline (6673.250 us; speedup 1.0000x reference)
//
#include <hip/hip_runtime.h>
#include <math.h>

#define NN 4096
#define TT 365
#define FF 16
#define HH 32

typedef _Float16 f16;
typedef __attribute__((ext_vector_type(8))) _Float16 f16x8;
typedef __attribute__((ext_vector_type(4))) float f32x4;

__device__ __forceinline__ float sigf(float x){ return 1.0f/(1.0f+__expf(-x)); }
__device__ __forceinline__ float thf(float x){
    x = fminf(fmaxf(x,-15.0f),15.0f);
    float e = __expf(2.0f*x);
    return (e-1.0f)/(e+1.0f);
}

// Pre-pack A (fp32 [4096][4096]) into MFMA A-fragment order, single fp16.
// Fragment addr (f16x8 units): (band*128 + kt)*64 + lane
//   lane&15 = local row m, lane>>4 = k-subgroup (8 consecutive k each).
__global__ __launch_bounds__(256)
void prep_A(const float* __restrict__ A, f16* __restrict__ Af){
    size_t i = (size_t)blockIdx.x*256 + threadIdx.x;   // 2,097,152 f16x8 frags
    int lane = (int)(i & 63);
    int kt   = (int)((i>>6) & 127);
    int rb   = (int)(i>>13);
    int m  = rb*16 + (lane&15);
    int k0 = kt*32 + ((lane>>4)<<3);
    const float* src = A + (size_t)m*NN + k0;
    float4 a = *(const float4*)src;
    float4 b = *(const float4*)(src+4);
    float v[8] = {a.x,a.y,a.z,a.w,b.x,b.y,b.z,b.w};
    f16x8 vh;
    #pragma unroll
    for (int j=0;j<8;++j) vh[j] = (f16)v[j];
    ((f16x8*)Af)[i] = vh;
}

// Initial G (h=c=0 -> cols = biases), fragment-ordered fp16; zero h/c state.
// B-fragment addr (f16 units): ((kt*4 + ct)*64 + (n&15) + ((kr>>3)<<4))*8 + (kr&7)
__global__ __launch_bounds__(256)
void init_G(f16* __restrict__ G, float* __restrict__ hs, float* __restrict__ cs,
            const float* __restrict__ bgh, const float* __restrict__ bgc){
    int i = blockIdx.x*256 + threadIdx.x;   // k*64+n
    int k = i>>6, n = i&63;
    float v = (n<HH) ? bgh[n] : bgc[n-HH];
    int kt = k>>5, kr = k&31;
    size_t idx = (((size_t)kt*4 + (n>>4))*64 + ((n&15) + ((kr>>3)<<4)))*8 + (kr&7);
    G[idx] = (f16)v;
    if (i < NN*HH){ hs[i]=0.f; cs[i]=0.f; }
}

// MM partial kernel: grid 1024 = 128 band-pairs x 8 k-slices, 256 threads.
// Block covers 32 rows (2 bands) x 512 k; wave w covers 4 kt (G loads reused
// across both bands -> 6 loads : 8 MFMAs). 2-stage LDS reduce of 4 waves,
// then fp32 partial slab write to Pbuf[kq][band][16][64].
__global__ __launch_bounds__(256, 6)
void mm_kernel(const f16* __restrict__ Af, const f16* __restrict__ Gin,
               float* __restrict__ Pbuf)
{
    __shared__ float red[4096];          // 16 KB
    const int tid  = threadIdx.x;
    const int w    = tid >> 6;           // wave 0..3
    const int lane = tid & 63;
    const int pair = blockIdx.x >> 3;    // 0..127
    const int kq   = blockIdx.x & 7;     // k-slice 0..7 (16 kt each)
    const int band0 = pair*2, band1 = pair*2 + 1;
    const int ktBeg = kq*16 + w*4;

    const f16x8* Ahp = (const f16x8*)Af;
    const f16x8* Gf  = (const f16x8*)Gin;
    size_t a0 = ((size_t)band0*128 + ktBeg)*64 + lane;
    size_t a1 = ((size_t)band1*128 + ktBeg)*64 + lane;
    size_t g  = (size_t)ktBeg*256 + lane;

    f32x4 acc0[4] = {}, acc1[4] = {};
    #pragma unroll
    for (int kt = 0; kt < 4; ++kt, a0 += 64, a1 += 64, g += 256){
        f16x8 A0 = Ahp[a0], A1 = Ahp[a1];
        f16x8 g0 = Gf[g], g1 = Gf[g+64], g2 = Gf[g+128], g3 = Gf[g+192];
        acc0[0] = __builtin_amdgcn_mfma_f32_16x16x32_f16(A0,g0,acc0[0],0,0,0);
        acc0[1] = __builtin_amdgcn_mfma_f32_16x16x32_f16(A0,g1,acc0[1],0,0,0);
        acc0[2] = __builtin_amdgcn_mfma_f32_16x16x32_f16(A0,g2,acc0[2],0,0,0);
        acc0[3] = __builtin_amdgcn_mfma_f32_16x16x32_f16(A0,g3,acc0[3],0,0,0);
        acc1[0] = __builtin_amdgcn_mfma_f32_16x16x32_f16(A1,g0,acc1[0],0,0,0);
        acc1[1] = __builtin_amdgcn_mfma_f32_16x16x32_f16(A1,g1,acc1[1],0,0,0);
        acc1[2] = __builtin_amdgcn_mfma_f32_16x16x32_f16(A1,g2,acc1[2],0,0,0);
        acc1[3] = __builtin_amdgcn_mfma_f32_16x16x32_f16(A1,g3,acc1[3],0,0,0);
    }
    // C/D layout (m89): col = lane&15, row = (lane>>4)*4 + reg
    const int mr = (lane>>4)<<2, mc = lane&15;
    if (w < 2){
        #pragma unroll
        for (int ct = 0; ct < 4; ++ct)
            #pragma unroll
            for (int r = 0; r < 4; ++r){
                red[w*2048 +        (mr+r)*64 + ct*16 + mc] = acc0[ct][r];
                red[w*2048 + 1024 + (mr+r)*64 + ct*16 + mc] = acc1[ct][r];
            }
    }
    __syncthreads();
    if (w >= 2){
        #pragma unroll
        for (int ct = 0; ct < 4; ++ct)
            #pragma unroll
            for (int r = 0; r < 4; ++r){
                red[(w-2)*2048 +        (mr+r)*64 + ct*16 + mc] += acc0[ct][r];
                red[(w-2)*2048 + 1024 + (mr+r)*64 + ct*16 + mc] += acc1[ct][r];
            }
    }
    __syncthreads();
    #pragma unroll
    for (int q = 0; q < 8; ++q){
        int e = tid + q*256;             // 0..2047 (band01*1024 + elem)
        float s = red[e] + red[2048 + e];
        int bnd = e >> 10;
        Pbuf[(size_t)kq*262144 + (size_t)(band0 + bnd)*1024 + (e & 1023)] = s;
    }
}

// Cell kernel: grid 256 bands x 512 threads. Sums the 8 k-slice partials,
// tanh, then row-local LSTM + fusion + next-G fragment write + output head.
// All cross-thread LDS traffic stays within a 32-lane row group -> no barriers.
__global__ __launch_bounds__(512)
void cell_kernel(const float* __restrict__ Pbuf,
                 const float* __restrict__ x, const float* __restrict__ W_out,
                 const float* __restrict__ b_out,
                 const float* __restrict__ Wgh, const float* __restrict__ bgh,
                 const float* __restrict__ Wgc, const float* __restrict__ bgc,
                 const float* __restrict__ Whc, const float* __restrict__ Whp,
                 const float* __restrict__ bh,
                 const float* __restrict__ Wcc, const float* __restrict__ Wcp,
                 const float* __restrict__ bc,
                 const float* __restrict__ K, const float* __restrict__ R,
                 const float* __restrict__ bias,
                 f16* __restrict__ Gout,
                 float* __restrict__ h_state, float* __restrict__ c_state,
                 float* __restrict__ out, int t)
{
    __shared__ float smem[6000];         // 24 KB
    float* gts    = smem;                // [16][129]
    float* hgcg   = smem + 2064;         // [16][65]
    float* hprevL = smem + 3104;         // [16][33]
    float* xs     = smem + 3632;         // [16][16]
    float* hcur   = smem + 3888;         // [16][33]
    float* ccur   = smem + 4416;
    float* hupd   = smem + 4944;
    float* cupd   = smem + 5472;

    const int tid = threadIdx.x;
    const int r2  = tid >> 5;            // local row 0..15
    const int j   = tid & 31;            // h-dim 0..31
    const int band = blockIdx.x;
    const int row = band*16 + r2;

    // sum 8 k-slice partials + tanh for cols j and j+32
    #pragma unroll
    for (int half = 0; half < 2; ++half){
        int n = j + half*32;
        float s = 0.f;
        #pragma unroll
        for (int q = 0; q < 8; ++q)
            s += Pbuf[(size_t)q*262144 + (size_t)band*1024 + r2*64 + n];
        hgcg[r2*65 + n] = thf(s);
    }

    float hp = h_state[(size_t)row*HH + j];
    hprevL[r2*33 + j] = hp;
    if (j < 16) xs[r2*16 + j] = x[((size_t)row*TT + t)*FF + j];

    // gates: thread computes gate cols [j*4, j*4+4)
    float g4[4];
    #pragma unroll
    for (int q = 0; q < 4; ++q) g4[q] = bias[j*4 + q];
    #pragma unroll
    for (int f = 0; f < FF; ++f){
        float xv = xs[r2*16 + f];
        float4 k4 = *(const float4*)(K + f*128 + j*4);
        g4[0] += xv*k4.x; g4[1] += xv*k4.y; g4[2] += xv*k4.z; g4[3] += xv*k4.w;
    }
    #pragma unroll
    for (int i = 0; i < HH; ++i){
        float hv = hprevL[r2*33 + i];
        float4 r4 = *(const float4*)(R + i*128 + j*4);
        g4[0] += hv*r4.x; g4[1] += hv*r4.y; g4[2] += hv*r4.z; g4[3] += hv*r4.w;
    }
    #pragma unroll
    for (int q = 0; q < 4; ++q) gts[r2*129 + j*4 + q] = g4[q];

    // LSTM cell, dim j (gate order i,f,g,o)
    float gi = gts[r2*129 + j],      gf = gts[r2*129 + 32 + j];
    float gg = gts[r2*129 + 64 + j], go = gts[r2*129 + 96 + j];
    float cp = c_state[(size_t)row*HH + j];
    float cc = sigf(gf)*cp + sigf(gi)*thf(gg);
    float hc = sigf(go)*thf(cc);
    hcur[r2*33 + j] = hc;
    ccur[r2*33 + j] = cc;

    // fusion
    float s = bh[j], u = bc[j];
    #pragma unroll
    for (int i = 0; i < HH; ++i){
        float hcv = hcur[r2*33 + i], hgv = hgcg[r2*65 + i];
        float ccv = ccur[r2*33 + i], cgv = hgcg[r2*65 + 32 + i];
        s += hcv*Whc[i*32 + j] + hgv*Whp[i*32 + j];
        u += ccv*Wcc[i*32 + j] + cgv*Wcp[i*32 + j];
    }
    float hu = sigf(s), cu = sigf(u);
    hupd[r2*33 + j] = hu;
    cupd[r2*33 + j] = cu;
    h_state[(size_t)row*HH + j] = hu;
    c_state[(size_t)row*HH + j] = cu;

    // G(t+1), written straight into B-fragment order
    float gh = bgh[j], gc = bgc[j];
    #pragma unroll
    for (int i = 0; i < HH; ++i){
        float hv = hupd[r2*33 + i], cv = cupd[r2*33 + i];
        gh += hv*Wgh[i*32 + j];
        gc += cv*Wgc[i*32 + j];
    }
    {
        const int kt = row>>5, kr = row&31;
        const size_t tb = ((size_t)kt*4)*64;
        size_t i0 = (tb + (size_t)(j>>4)*64 + ((j&15) + ((kr>>3)<<4)))*8 + (kr&7);
        size_t i1 = (tb + (size_t)((HH+j)>>4)*64 + ((j&15) + ((kr>>3)<<4)))*8 + (kr&7);
        Gout[i0] = (f16)gh;
        Gout[i1] = (f16)gc;
    }

    // fused output head
    float p = hu * W_out[j];
    #pragma unroll
    for (int off = 16; off; off >>= 1) p += __shfl_down(p, off, 32);
    if (j == 0) out[(size_t)t*NN + row] = p + b_out[0];
}

extern "C" void kernel_launch(void* const* d_in, const int* in_sizes, int n_in,
                              void* d_out, int out_size, void* d_ws, size_t ws_size,
                              hipStream_t stream)
{
    const float* x     = (const float*)d_in[0];
    const float* A     = (const float*)d_in[1];
    const float* W_out = (const float*)d_in[2];
    const float* b_out = (const float*)d_in[3];
    const float* Wgh   = (const float*)d_in[4];
    const float* bgh   = (const float*)d_in[5];
    const float* Wgc   = (const float*)d_in[6];
    const float* bgc   = (const float*)d_in[7];
    const float* Whc   = (const float*)d_in[8];
    const float* Whp   = (const float*)d_in[9];
    const float* bh    = (const float*)d_in[10];
    const float* Wcc   = (const float*)d_in[11];
    const float* Wcp   = (const float*)d_in[12];
    const float* bc    = (const float*)d_in[13];
    const float* K     = (const float*)d_in[14];
    const float* R     = (const float*)d_in[15];
    const float* bias  = (const float*)d_in[16];
    float* out = (float*)d_out;

    // ws: Af 32MB | G double-buffer 2x512KB | Pbuf 8MB | h/c state 1MB
    f16* Af = (f16*)d_ws;
    f16* G0 = Af + (size_t)NN*NN;
    f16* G1 = G0 + (size_t)NN*64;
    float* Pbuf = (float*)(G1 + (size_t)NN*64);
    float* hs = Pbuf + (size_t)8*NN*64;
    float* cs = hs + (size_t)NN*HH;

    prep_A<<<dim3(8192), dim3(256), 0, stream>>>(A, Af);
    init_G<<<dim3(1024), dim3(256), 0, stream>>>(G0, hs, cs, bgh, bgc);

    for (int t = 0; t < TT; ++t){
        const f16* Gin = (t & 1) ? G1 : G0;
        f16*       Gout = (t & 1) ? G0 : G1;
        mm_kernel<<<dim3(1024), dim3(256), 0, stream>>>(Af, Gin, Pbuf);
        cell_kernel<<<dim3(256), dim3(512), 0, stream>>>(
            Pbuf, x, W_out, b_out, Wgh, bgh, Wgc, bgc, Whc, Whp, bh,
            Wcc, Wcp, bc, K, R, bias, Gout, hs, cs, out, t);
    }
}